// Round 9
// baseline (55.311 us; speedup 1.0000x reference)
//
#include <hip/hip_runtime.h>

// ChebychevTransform: x[8,256,256,8] f32 -> out[8,256,256,128] f32
// out[b,h,w, c*16+p*4+k] = sum_{j,i} T[p][j]*T[k][i]*xpad[b,h+i-1,w+j-1,c]
//
// R2: nontemporal 16B lane-strided stores -> partial-line bursts, 728MB. 337us.
// R3: cached stores, L2 merges -> 268MB, but 4x store transactions. 88.9us.
// R4: LDS-staged store transpose (full-line wave stores). 55.6us.
// R5: interior fast-path + butterfly DCT + nt full-line stores. 50.5us.
// R6: single-wave blocks, no barrier. 48.1us.  <- best
// R7: 4 indep waves/block: 49.4us (occupancy not the cap).
// R8: two tiles/wave: 52.6us (VGPR + serial preamble cost > ILP gain).
// R9: R6 exactly, but PLAIN cached stores instead of nontemporal — isolate
//     the nt-direct vs L2-buffered write-drain path (fill kernel does 7TB/s
//     through L2). Watch FETCH_SIZE for input-eviction side effect.

#define H_DIM 256
#define W_DIM 256
#define C_DIM 8
#define B_DIM 8

typedef float f32x4 __attribute__((ext_vector_type(4)));

// 4-point DCT-I butterfly: y = T*v with
// T = [[1/6,1/3,1/3,1/6],[1/3,1/3,-1/3,-1/3],[1/3,-1/3,-1/3,1/3],[1/3,-2/3,2/3,-1/3]]
__device__ __forceinline__ void cheb4(const float v0, const float v1,
                                      const float v2, const float v3,
                                      float& y0, float& y1, float& y2, float& y3) {
    const float a = v0 + v3;
    const float bb = v1 + v2;
    const float d = v0 - v3;
    const float e = v1 - v2;
    y0 = a * (1.f / 6.f) + bb * (1.f / 3.f);
    y1 = (d + e) * (1.f / 3.f);
    y2 = (a - bb) * (1.f / 3.f);
    y3 = d * (1.f / 3.f) - e * (2.f / 3.f);
}

__global__ __launch_bounds__(64) void cheb_kernel(const float* __restrict__ x,
                                                  float* __restrict__ out) {
    __shared__ f32x4 lds[256];            // 4 KB: block's 1024-float out chunk

    const int t = threadIdx.x;            // 0..63, exactly one wave
    const int bid = blockIdx.x;
    // tid = bid*64+t = ((b*256 + h)*256 + w)*8 + c
    const int c = t & 7;
    const int w = ((bid & 31) << 3) | (t >> 3);
    const int h = (bid >> 5) & 255;
    const int b = bid >> 13;

    // Load 4x4 patch: v[j][i] = xpad[b, h+i-1, w+j-1, c] (zero outside).
    float v[4][4];
    const bool interior = (h >= 1) & (h <= H_DIM - 3) & (w >= 1) & (w <= W_DIM - 3);
    if (interior) {
        const float* p0 = x + (((((size_t)b * H_DIM + (h - 1)) * W_DIM) + (w - 1)) * C_DIM) + c;
#pragma unroll
        for (int i = 0; i < 4; ++i) {
#pragma unroll
            for (int j = 0; j < 4; ++j) {
                v[j][i] = p0[i * (W_DIM * C_DIM) + j * C_DIM];
            }
        }
    } else {
#pragma unroll
        for (int i = 0; i < 4; ++i) {
            const int hh = h + i - 1;
            const bool hok = (unsigned)hh < (unsigned)H_DIM;
            const int hc = min(max(hh, 0), H_DIM - 1);
#pragma unroll
            for (int j = 0; j < 4; ++j) {
                const int ww = w + j - 1;
                const bool ok = hok && ((unsigned)ww < (unsigned)W_DIM);
                const int wc = min(max(ww, 0), W_DIM - 1);
                const size_t idx = ((((size_t)b * H_DIM + hc) * W_DIM + wc) * C_DIM) + c;
                const float val = x[idx];   // address always in-bounds (clamped)
                v[j][i] = ok ? val : 0.0f;
            }
        }
    }

    // Row transform (over i): tmp[j][k] = sum_i T[k][i]*v[j][i]
    float tmp[4][4];
#pragma unroll
    for (int j = 0; j < 4; ++j)
        cheb4(v[j][0], v[j][1], v[j][2], v[j][3],
              tmp[j][0], tmp[j][1], tmp[j][2], tmp[j][3]);

    // Col transform (over j): o[p][k] = sum_j T[p][j]*tmp[j][k]
    float o[4][4];
#pragma unroll
    for (int k = 0; k < 4; ++k)
        cheb4(tmp[0][k], tmp[1][k], tmp[2][k], tmp[3][k],
              o[0][k], o[1][k], o[2][k], o[3][k]);

    // Stash in LDS, XOR-swizzled so both LDS phases are bank-uniform.
    // Single wave: no __syncthreads needed — lgkmcnt orders the RAW.
#pragma unroll
    for (int p = 0; p < 4; ++p) {
        f32x4 r;
#pragma unroll
        for (int k = 0; k < 4; ++k) r[k] = o[p][k];
        lds[p * 64 + (t ^ p)] = r;
    }

    // Coalesced store: iteration s, thread t emits chunk f4 index q = s*64+t,
    // contiguous 1KB per wave store, full 64B lines. Plain cached stores:
    // L2-buffered drain (the path fillBufferAligned sustains 7 TB/s on).
    f32x4* o4 = reinterpret_cast<f32x4*>(out) + (size_t)bid * 256;
#pragma unroll
    for (int s = 0; s < 4; ++s) {
        const int q = s * 64 + t;
        const int p = q & 3;            // == t & 3
        const int tp = q >> 2;
        o4[q] = lds[p * 64 + (tp ^ p)];
    }
}

extern "C" void kernel_launch(void* const* d_in, const int* in_sizes, int n_in,
                              void* d_out, int out_size, void* d_ws, size_t ws_size,
                              hipStream_t stream) {
    const float* x = (const float*)d_in[0];
    float* out = (float*)d_out;
    const int total_threads = B_DIM * H_DIM * W_DIM * C_DIM;  // 4,194,304
    const int block = 64;
    const int grid = total_threads / block;                   // 65536
    cheb_kernel<<<grid, block, 0, stream>>>(x, out);
}

// Round 10
// 47.578 us; speedup vs baseline: 1.1625x; 1.1625x over previous
//
#include <hip/hip_runtime.h>

// ChebychevTransform: x[8,256,256,8] f32 -> out[8,256,256,128] f32
// out[b,h,w, c*16+p*4+k] = sum_{j,i} T[p][j]*T[k][i]*xpad[b,h+i-1,w+j-1,c]
//
// Ladder: R2 nt partial-line stores 337us -> R3 cached+L2-merge 88.9us ->
// R4 LDS store-transpose 55.6us -> R5 fastpath+butterfly+nt 50.5us ->
// R6 single-wave blocks no-barrier 48.1us (BEST) -> R7 4-wave 49.4 (x) ->
// R8 2 tiles/wave 52.6 (x) -> R9 cached stores 55.3 (x; nt-direct wins).
// R10: revert to R6. 284MB @ 48.1us = 5.9 TB/s = 94% of 6.3 TB/s achievable
// ceiling -> roofline. Write bytes are mandatory (write-once output payload),
// compute is ~5% VALUBusy. Done.

#define H_DIM 256
#define W_DIM 256
#define C_DIM 8
#define B_DIM 8

typedef float f32x4 __attribute__((ext_vector_type(4)));

// 4-point DCT-I butterfly: y = T*v with
// T = [[1/6,1/3,1/3,1/6],[1/3,1/3,-1/3,-1/3],[1/3,-1/3,-1/3,1/3],[1/3,-2/3,2/3,-1/3]]
__device__ __forceinline__ void cheb4(const float v0, const float v1,
                                      const float v2, const float v3,
                                      float& y0, float& y1, float& y2, float& y3) {
    const float a = v0 + v3;
    const float bb = v1 + v2;
    const float d = v0 - v3;
    const float e = v1 - v2;
    y0 = a * (1.f / 6.f) + bb * (1.f / 3.f);
    y1 = (d + e) * (1.f / 3.f);
    y2 = (a - bb) * (1.f / 3.f);
    y3 = d * (1.f / 3.f) - e * (2.f / 3.f);
}

__global__ __launch_bounds__(64) void cheb_kernel(const float* __restrict__ x,
                                                  float* __restrict__ out) {
    __shared__ f32x4 lds[256];            // 4 KB: block's 1024-float out chunk

    const int t = threadIdx.x;            // 0..63, exactly one wave
    const int bid = blockIdx.x;
    // tid = bid*64+t = ((b*256 + h)*256 + w)*8 + c
    const int c = t & 7;
    const int w = ((bid & 31) << 3) | (t >> 3);
    const int h = (bid >> 5) & 255;
    const int b = bid >> 13;

    // Load 4x4 patch: v[j][i] = xpad[b, h+i-1, w+j-1, c] (zero outside).
    float v[4][4];
    const bool interior = (h >= 1) & (h <= H_DIM - 3) & (w >= 1) & (w <= W_DIM - 3);
    if (interior) {
        const float* p0 = x + (((((size_t)b * H_DIM + (h - 1)) * W_DIM) + (w - 1)) * C_DIM) + c;
#pragma unroll
        for (int i = 0; i < 4; ++i) {
#pragma unroll
            for (int j = 0; j < 4; ++j) {
                v[j][i] = p0[i * (W_DIM * C_DIM) + j * C_DIM];
            }
        }
    } else {
#pragma unroll
        for (int i = 0; i < 4; ++i) {
            const int hh = h + i - 1;
            const bool hok = (unsigned)hh < (unsigned)H_DIM;
            const int hc = min(max(hh, 0), H_DIM - 1);
#pragma unroll
            for (int j = 0; j < 4; ++j) {
                const int ww = w + j - 1;
                const bool ok = hok && ((unsigned)ww < (unsigned)W_DIM);
                const int wc = min(max(ww, 0), W_DIM - 1);
                const size_t idx = ((((size_t)b * H_DIM + hc) * W_DIM + wc) * C_DIM) + c;
                const float val = x[idx];   // address always in-bounds (clamped)
                v[j][i] = ok ? val : 0.0f;
            }
        }
    }

    // Row transform (over i): tmp[j][k] = sum_i T[k][i]*v[j][i]
    float tmp[4][4];
#pragma unroll
    for (int j = 0; j < 4; ++j)
        cheb4(v[j][0], v[j][1], v[j][2], v[j][3],
              tmp[j][0], tmp[j][1], tmp[j][2], tmp[j][3]);

    // Col transform (over j): o[p][k] = sum_j T[p][j]*tmp[j][k]
    float o[4][4];
#pragma unroll
    for (int k = 0; k < 4; ++k)
        cheb4(tmp[0][k], tmp[1][k], tmp[2][k], tmp[3][k],
              o[0][k], o[1][k], o[2][k], o[3][k]);

    // Stash in LDS, XOR-swizzled so both LDS phases are bank-uniform.
    // Single wave: no __syncthreads needed — lgkmcnt orders the RAW.
#pragma unroll
    for (int p = 0; p < 4; ++p) {
        f32x4 r;
#pragma unroll
        for (int k = 0; k < 4; ++k) r[k] = o[p][k];
        lds[p * 64 + (t ^ p)] = r;
    }

    // Coalesced store: iteration s, thread t emits chunk f4 index q = s*64+t,
    // which producer thread t'=q>>2 stored as its p=(q&3)-th f4. Contiguous
    // 1KB per wave store, full 64B lines -> nontemporal-direct drain (beats
    // the L2-buffered path by ~13% for this write-once stream; R9 isolated).
    f32x4* o4 = reinterpret_cast<f32x4*>(out) + (size_t)bid * 256;
#pragma unroll
    for (int s = 0; s < 4; ++s) {
        const int q = s * 64 + t;
        const int p = q & 3;            // == t & 3
        const int tp = q >> 2;
        f32x4 r = lds[p * 64 + (tp ^ p)];
        __builtin_nontemporal_store(r, &o4[q]);
    }
}

extern "C" void kernel_launch(void* const* d_in, const int* in_sizes, int n_in,
                              void* d_out, int out_size, void* d_ws, size_t ws_size,
                              hipStream_t stream) {
    const float* x = (const float*)d_in[0];
    float* out = (float*)d_out;
    const int total_threads = B_DIM * H_DIM * W_DIM * C_DIM;  // 4,194,304
    const int block = 64;
    const int grid = total_threads / block;                   // 65536
    cheb_kernel<<<grid, block, 0, stream>>>(x, out);
}